// Round 5
// baseline (350.364 us; speedup 1.0000x reference)
//
#include <hip/hip_runtime.h>

typedef _Float16 f16;
typedef __attribute__((ext_vector_type(8))) _Float16 f16x8;
typedef __attribute__((ext_vector_type(4))) _Float16 f16x4;
typedef __attribute__((ext_vector_type(4))) float floatx4;

#define MFMA16(a, b, c) __builtin_amdgcn_mfma_f32_16x16x32_f16(a, b, c, 0, 0, 0)

#define BATCH 32
#define LQ 512
#define LK 512
#define DIM 1024

// async global->LDS, 16B per lane. LDS dest must be base + lane*16 within wave.
__device__ __forceinline__ void glds16(const void* g, void* l) {
    __builtin_amdgcn_global_load_lds(
        (const __attribute__((address_space(1))) unsigned int*)g,
        (__attribute__((address_space(3))) unsigned int*)l, 16, 0, 0);
}

// ---------------------------------------------------------------------------
// K0a stage 1: partial[ec][d] = sum_{e in 64-chunk ec} W[e][d]*bias[e]
// ---------------------------------------------------------------------------
__global__ __launch_bounds__(256) void k_cvec1(const float* __restrict__ W,
                                               const float* __restrict__ bias,
                                               float* __restrict__ partial) {
    __shared__ float red[256];
    int t = threadIdx.x;
    int dd = t & 63, eg = t >> 6;
    int d = blockIdx.x * 64 + dd;
    int e0 = blockIdx.y * 64 + eg * 16;
    float s = 0.f;
#pragma unroll
    for (int i = 0; i < 16; ++i)
        s += W[(size_t)(e0 + i) * DIM + d] * bias[e0 + i];
    red[t] = s;
    __syncthreads();
    if (eg == 0)
        partial[blockIdx.y * DIM + d] =
            red[dd] + red[64 + dd] + red[128 + dd] + red[192 + dd];
}

// K0a stage 2: c[d] = sum_ec partial[ec][d]
__global__ __launch_bounds__(256) void k_cvec2(const float* __restrict__ partial,
                                               float* __restrict__ c) {
    int d = blockIdx.x * 256 + threadIdx.x;
    float s = 0.f;
#pragma unroll
    for (int j = 0; j < 16; ++j) s += partial[j * DIM + d];
    c[d] = s;
}

// ---------------------------------------------------------------------------
// K0b: Y16 = fp16(Y) and z[row] = c . Y[row]   (grid 4096 x 256)
// ---------------------------------------------------------------------------
__global__ __launch_bounds__(256) void k_prep_y(const float* __restrict__ Y,
                                                const float* __restrict__ c,
                                                f16* __restrict__ Y16,
                                                float* __restrict__ z) {
    int wid = threadIdx.x >> 6, lane = threadIdx.x & 63;
    int row = blockIdx.x * 4 + wid;
    const float* yr = Y + (size_t)row * DIM;
    f16* orow = Y16 + (size_t)row * DIM;
    float s = 0.f;
#pragma unroll
    for (int k = 0; k < 4; ++k) {
        int d = k * 256 + lane * 4;
        floatx4 v = *(const floatx4*)(yr + d);
        floatx4 cv = *(const floatx4*)(c + d);
        s += v[0] * cv[0] + v[1] * cv[1] + v[2] * cv[2] + v[3] * cv[3];
        f16x4 o;
        o[0] = (f16)v[0]; o[1] = (f16)v[1]; o[2] = (f16)v[2]; o[3] = (f16)v[3];
        *(f16x4*)(orow + d) = o;
    }
#pragma unroll
    for (int off = 32; off; off >>= 1) s += __shfl_down(s, off, 64);
    if (lane == 0) z[row] = s;
}

// ---------------------------------------------------------------------------
// K1: Gh = fp16(W^T W), single fp16 pass, SYMMETRY-halved: only i0<=j0
// blocks compute; epilogue writes the mirrored tile too. grid (16,16).
// ---------------------------------------------------------------------------
__global__ __launch_bounds__(256) void k_gram(const float* __restrict__ W,
                                              f16* __restrict__ Gh) {
    if (blockIdx.x > blockIdx.y) return;  // G symmetric: keep upper triangle
    __shared__ __align__(16) f16 As[64][40];
    __shared__ __align__(16) f16 Bs[64][40];
    int t = threadIdx.x;
    int lane = t & 63, wid = t >> 6;
    int ln15 = lane & 15, q = lane >> 4;
    int wr = (wid >> 1) * 32, wc = (wid & 1) * 32;
    int i0 = blockIdx.x * 64, j0 = blockIdx.y * 64;
    floatx4 acc[2][2] = {};
    for (int e0 = 0; e0 < DIM; e0 += 32) {
        __syncthreads();
        {
            int ee = t >> 3;
            int c8 = (t & 7) * 8;
            const float* src = W + (size_t)(e0 + ee) * DIM;
#pragma unroll
            for (int h = 0; h < 2; ++h) {
                floatx4 v = *(const floatx4*)(src + i0 + c8 + h * 4);
#pragma unroll
                for (int j = 0; j < 4; ++j) As[c8 + h * 4 + j][ee] = (f16)v[j];
                floatx4 u = *(const floatx4*)(src + j0 + c8 + h * 4);
#pragma unroll
                for (int j = 0; j < 4; ++j) Bs[c8 + h * 4 + j][ee] = (f16)u[j];
            }
        }
        __syncthreads();
        f16x8 a[2], b[2];
#pragma unroll
        for (int mi = 0; mi < 2; ++mi)
            a[mi] = *(const f16x8*)&As[wr + mi * 16 + ln15][q * 8];
#pragma unroll
        for (int ni = 0; ni < 2; ++ni)
            b[ni] = *(const f16x8*)&Bs[wc + ni * 16 + ln15][q * 8];
#pragma unroll
        for (int mi = 0; mi < 2; ++mi)
#pragma unroll
            for (int ni = 0; ni < 2; ++ni)
                acc[mi][ni] = MFMA16(a[mi], b[ni], acc[mi][ni]);
    }
#pragma unroll
    for (int mi = 0; mi < 2; ++mi)
#pragma unroll
        for (int ni = 0; ni < 2; ++ni)
#pragma unroll
            for (int r = 0; r < 4; ++r) {
                int i = i0 + wr + mi * 16 + q * 4 + r;
                int j = j0 + wc + ni * 16 + ln15;
                f16 h = (f16)acc[mi][ni][r];
                Gh[(size_t)i * DIM + j] = h;
                if (i0 != j0) Gh[(size_t)j * DIM + i] = h;  // mirror tile
            }
}

// ---------------------------------------------------------------------------
// K2: Th = fp16(X @ Gh). X read fp32 directly (xsplit fused): VGPR-path
// staging (load->cvt->ds_write) into 40-padded rows (bank-conflict-free
// frag reads); B stays glds. M=16384, N=K=1024, 128x128, BK=32.
// ---------------------------------------------------------------------------
__global__ __launch_bounds__(256) void k_tgemm(const float* __restrict__ X,
                                               const f16* __restrict__ Gh,
                                               f16* __restrict__ Th) {
    __shared__ __align__(16) f16 sA[128 * 40];  // 80B row stride: 2-way max
    __shared__ __align__(16) f16 sB[128 * 32];
    const int t = threadIdx.x;
    const int lane = t & 63, wid = t >> 6;
    const int ln15 = lane & 15, q = lane >> 4;
    const int wr = (wid >> 1) * 64, wc = (wid & 1) * 64;
    const int m0 = blockIdx.x * 128, n0 = blockIdx.y * 128;
    const int arow = t >> 1, akh = (t & 1) * 16;
    const float* asrc = X + (size_t)(m0 + arow) * DIM + akh;
    f16* adst = &sA[arow * 40 + akh];
    floatx4 acc[4][4] = {};
    for (int e0 = 0; e0 < DIM; e0 += 32) {
        // global X loads issued before barrier (no LDS dependence)
        floatx4 v0 = *(const floatx4*)(asrc + e0);
        floatx4 v1 = *(const floatx4*)(asrc + e0 + 4);
        floatx4 v2 = *(const floatx4*)(asrc + e0 + 8);
        floatx4 v3 = *(const floatx4*)(asrc + e0 + 12);
        __syncthreads();
#pragma unroll
        for (int is = 0; is < 2; ++is) {
            int ff = is * 4096 + t * 16;
            int row = ff >> 6, col = (ff & 63) >> 1;
            glds16(Gh + (size_t)(n0 + row) * DIM + e0 + col, (char*)sB + ff);
        }
        union { f16 h[16]; uint4 u[2]; } cv;
#pragma unroll
        for (int j = 0; j < 4; ++j) {
            cv.h[j] = (f16)v0[j];
            cv.h[4 + j] = (f16)v1[j];
            cv.h[8 + j] = (f16)v2[j];
            cv.h[12 + j] = (f16)v3[j];
        }
        *(uint4*)adst = cv.u[0];
        *(uint4*)(adst + 8) = cv.u[1];
        __syncthreads();
        f16x8 a[4];
#pragma unroll
        for (int mi = 0; mi < 4; ++mi)
            a[mi] = *(const f16x8*)&sA[(wr + mi * 16 + ln15) * 40 + q * 8];
#pragma unroll
        for (int ni = 0; ni < 4; ++ni) {
            f16x8 bv = *(const f16x8*)&sB[(wc + ni * 16 + ln15) * 32 + q * 8];
#pragma unroll
            for (int mi = 0; mi < 4; ++mi)
                acc[mi][ni] = MFMA16(a[mi], bv, acc[mi][ni]);
        }
    }
#pragma unroll
    for (int mi = 0; mi < 4; ++mi)
#pragma unroll
        for (int ni = 0; ni < 4; ++ni)
#pragma unroll
            for (int r = 0; r < 4; ++r)
                Th[(size_t)(m0 + wr + mi * 16 + q * 4 + r) * DIM +
                   n0 + wc + ni * 16 + ln15] = (f16)acc[mi][ni][r];
}

// ---------------------------------------------------------------------------
// K_yT: YT16[b][d][m] = Y16[b][m][d]   (grid (32,8,16), 64x64 tiles)
// ---------------------------------------------------------------------------
__global__ __launch_bounds__(256) void k_ytrans(const f16* __restrict__ Y16,
                                                f16* __restrict__ YT) {
    __shared__ __align__(16) f16 S[64][72];
    const int b = blockIdx.x, m0 = blockIdx.y * 64, d0 = blockIdx.z * 64;
    const int t = threadIdx.x;
    {
        int row = t >> 2, cg = (t & 3) * 16;
        const f16* src = Y16 + (size_t)(b * LK + m0 + row) * DIM + d0 + cg;
        *(uint4*)&S[row][cg] = *(const uint4*)src;
        *(uint4*)&S[row][cg + 8] = *(const uint4*)(src + 8);
    }
    __syncthreads();
    int dd = t >> 2, ms = (t & 3) * 16;
    union { f16 h[16]; uint4 u[2]; } o;
#pragma unroll
    for (int j = 0; j < 16; ++j) o.h[j] = S[ms + j][dd];
    f16* dst = YT + (size_t)(b * DIM + d0 + dd) * LK + m0 + ms;
    *(uint4*)dst = o.u[0];
    *(uint4*)(dst + 8) = o.u[1];
}

// ---------------------------------------------------------------------------
// K3: per (b, 32 q-rows): s = Th . Y16^T + z, softmax over 512 keys,
// write unnormalized P fp16 + row sums. grid (32,16), 512 thr (8 waves).
// l-tile 32 (was 64) -> 512 blocks -> 2 blocks/CU, 16 waves/CU.
// LDS: Th 2KB | Y 32KB contiguous (glds flat mapping), BK=32.
// ---------------------------------------------------------------------------
__global__ __launch_bounds__(512) void k_attn(const f16* __restrict__ Th,
                                              const f16* __restrict__ Y16,
                                              const float* __restrict__ Z,
                                              f16* __restrict__ P,
                                              float* __restrict__ Lsum) {
    __shared__ __align__(16) f16 sS[17408];  // 34816 B: Th 32x32 | Y 512x32
    __shared__ float redmax[32][8];
    __shared__ float redsum[32][8];
    const int b = blockIdx.x;
    const int l0 = blockIdx.y * 32;
    const int t = threadIdx.x;
    const int lane = t & 63, w = t >> 6;
    const int ln15 = lane & 15, q = lane >> 4;
    floatx4 acc[2][4] = {};

    for (int e0 = 0; e0 < DIM; e0 += 32) {
        __syncthreads();
#pragma unroll
        for (int is = 0; is < 5; ++is) {
            int ff = is * 8192 + t * 16;
            if (ff < 34816) {  // wave-uniform guard (last chunk: waves 0-1)
                const f16* g;
                if (ff < 2048) {
                    g = Th + (size_t)(b * LQ + l0 + (ff >> 6)) * DIM + e0 + ((ff & 63) >> 1);
                } else {
                    int f2 = ff - 2048;
                    g = Y16 + (size_t)(b * LK + (f2 >> 6)) * DIM + e0 + ((f2 & 63) >> 1);
                }
                glds16(g, (char*)sS + ff);
            }
        }
        __syncthreads();
        f16x8 th[2];
#pragma unroll
        for (int mi = 0; mi < 2; ++mi)
            th[mi] = *(const f16x8*)&sS[(mi * 16 + ln15) * 32 + q * 8];
#pragma unroll
        for (int ni = 0; ni < 4; ++ni) {
            f16x8 y = *(const f16x8*)&sS[1024 + (w * 64 + ni * 16 + ln15) * 32 + q * 8];
#pragma unroll
            for (int mi = 0; mi < 2; ++mi)
                acc[mi][ni] = MFMA16(th[mi], y, acc[mi][ni]);
        }
    }

    // ---- softmax over 512 cols (8 waves x 64 cols) ----
    float zv[4];
#pragma unroll
    for (int ni = 0; ni < 4; ++ni) zv[ni] = Z[b * LK + w * 64 + ni * 16 + ln15];

    float rmx[2][4];
#pragma unroll
    for (int mi = 0; mi < 2; ++mi)
#pragma unroll
        for (int r = 0; r < 4; ++r) {
            float m = -3.0e38f;
#pragma unroll
            for (int ni = 0; ni < 4; ++ni) m = fmaxf(m, acc[mi][ni][r] + zv[ni]);
#pragma unroll
            for (int off = 1; off < 16; off <<= 1) m = fmaxf(m, __shfl_xor(m, off, 64));
            rmx[mi][r] = m;
        }
    if (ln15 == 0) {
#pragma unroll
        for (int mi = 0; mi < 2; ++mi)
#pragma unroll
            for (int r = 0; r < 4; ++r) redmax[mi * 16 + q * 4 + r][w] = rmx[mi][r];
    }
    __syncthreads();
#pragma unroll
    for (int mi = 0; mi < 2; ++mi)
#pragma unroll
        for (int r = 0; r < 4; ++r) {
            int row = mi * 16 + q * 4 + r;
            float m = redmax[row][0];
#pragma unroll
            for (int j = 1; j < 8; ++j) m = fmaxf(m, redmax[row][j]);
            rmx[mi][r] = m;
        }
    float rsm[2][4] = {};
#pragma unroll
    for (int mi = 0; mi < 2; ++mi)
#pragma unroll
        for (int ni = 0; ni < 4; ++ni)
#pragma unroll
            for (int r = 0; r < 4; ++r) {
                float e = __expf(acc[mi][ni][r] + zv[ni] - rmx[mi][r]);
                acc[mi][ni][r] = e;
                rsm[mi][r] += e;
            }
#pragma unroll
    for (int mi = 0; mi < 2; ++mi)
#pragma unroll
        for (int r = 0; r < 4; ++r) {
            float s = rsm[mi][r];
#pragma unroll
            for (int off = 1; off < 16; off <<= 1) s += __shfl_xor(s, off, 64);
            rsm[mi][r] = s;
        }
    if (ln15 == 0) {
#pragma unroll
        for (int mi = 0; mi < 2; ++mi)
#pragma unroll
            for (int r = 0; r < 4; ++r) redsum[mi * 16 + q * 4 + r][w] = rsm[mi][r];
    }
    __syncthreads();
    if (w == 0 && ln15 == 0) {
#pragma unroll
        for (int mi = 0; mi < 2; ++mi)
#pragma unroll
            for (int r = 0; r < 4; ++r) {
                int row = mi * 16 + q * 4 + r;
                float s = 0.f;
#pragma unroll
                for (int j = 0; j < 8; ++j) s += redsum[row][j];
                Lsum[b * LQ + l0 + row] = s;
            }
    }
#pragma unroll
    for (int mi = 0; mi < 2; ++mi)
#pragma unroll
        for (int ni = 0; ni < 4; ++ni)
#pragma unroll
            for (int r = 0; r < 4; ++r) {
                int row = l0 + mi * 16 + q * 4 + r;
                int col = w * 64 + ni * 16 + ln15;
                P[(size_t)(b * LQ + row) * LK + col] = (f16)acc[mi][ni][r];
            }
}

// ---------------------------------------------------------------------------
// K4: O = (P @ y) / Lsum  via YT16. grid (32,4,8), 128x128 tile, BK=32, glds.
// ---------------------------------------------------------------------------
__global__ __launch_bounds__(256) void k_pv(const f16* __restrict__ P,
                                            const f16* __restrict__ YT,
                                            const float* __restrict__ Lsum,
                                            float* __restrict__ O) {
    __shared__ __align__(16) f16 sA[128 * 32];
    __shared__ __align__(16) f16 sB[128 * 32];
    const int t = threadIdx.x;
    const int lane = t & 63, wid = t >> 6;
    const int ln15 = lane & 15, q = lane >> 4;
    const int wr = (wid >> 1) * 64, wc = (wid & 1) * 64;
    const int b = blockIdx.x, m0 = blockIdx.y * 128, n0 = blockIdx.z * 128;
    floatx4 acc[4][4] = {};
    for (int k0 = 0; k0 < LK; k0 += 32) {
        __syncthreads();
#pragma unroll
        for (int is = 0; is < 2; ++is) {
            int ff = is * 4096 + t * 16;
            int row = ff >> 6, col = (ff & 63) >> 1;
            glds16(P + (size_t)(b * LQ + m0 + row) * LK + k0 + col, (char*)sA + ff);
            glds16(YT + (size_t)(b * DIM + n0 + row) * LK + k0 + col, (char*)sB + ff);
        }
        __syncthreads();
        f16x8 a[4];
#pragma unroll
        for (int mi = 0; mi < 4; ++mi)
            a[mi] = *(const f16x8*)&sA[(wr + mi * 16 + ln15) * 32 + q * 8];
#pragma unroll
        for (int ni = 0; ni < 4; ++ni) {
            f16x8 bv = *(const f16x8*)&sB[(wc + ni * 16 + ln15) * 32 + q * 8];
#pragma unroll
            for (int mi = 0; mi < 4; ++mi) acc[mi][ni] = MFMA16(a[mi], bv, acc[mi][ni]);
        }
    }
    float invl[4][4];
#pragma unroll
    for (int mi = 0; mi < 4; ++mi)
#pragma unroll
        for (int r = 0; r < 4; ++r)
            invl[mi][r] = 1.0f / Lsum[b * LQ + m0 + wr + mi * 16 + q * 4 + r];
#pragma unroll
    for (int mi = 0; mi < 4; ++mi)
#pragma unroll
        for (int ni = 0; ni < 4; ++ni)
#pragma unroll
            for (int r = 0; r < 4; ++r)
                O[(size_t)(b * LQ + m0 + wr + mi * 16 + q * 4 + r) * DIM +
                  n0 + wc + ni * 16 + ln15] = acc[mi][ni][r] * invl[mi][r];
}

// ---------------------------------------------------------------------------
// Workspace layout (bytes), total ~86 MiB:
//   YT16: 0        fp16 [32][1024][512] (33,554,432)
//   Y16:  33554432 fp16 [32][512][1024] (33,554,432)
//   P:    67108864 fp16 [32][512][512]  (16,777,216)
//   Gh:   83886080 (2,097,152)
//   c:    85983232 (4096)  z: 85987328 (65536)  L: 86052864 (65536)
//   partial: 86118400 (65536)
// d_out doubles as Th fp16 scratch (32 MB) between k_tgemm and k_attn;
// k_pv overwrites it with the final fp32 result.
// ---------------------------------------------------------------------------
extern "C" void kernel_launch(void* const* d_in, const int* in_sizes, int n_in,
                              void* d_out, int out_size, void* d_ws, size_t ws_size,
                              hipStream_t stream) {
    const float* ix = (const float*)d_in[0];
    const float* io = (const float*)d_in[1];
    const float* W = (const float*)d_in[2];
    const float* bb = (const float*)d_in[3];
    float* out = (float*)d_out;
    char* ws = (char*)d_ws;

    f16* YT16 = (f16*)(ws);
    f16* Y16 = (f16*)(ws + 33554432);
    f16* P = (f16*)(ws + 67108864);
    f16* Gh = (f16*)(ws + 83886080);
    float* c = (float*)(ws + 85983232);
    float* z = (float*)(ws + 85987328);
    float* L = (float*)(ws + 86052864);
    float* partial = (float*)(ws + 86118400);

    f16* Th = (f16*)d_out;

    k_cvec1<<<dim3(16, 16), dim3(256), 0, stream>>>(W, bb, partial);
    k_cvec2<<<dim3(4), dim3(256), 0, stream>>>(partial, c);
    k_gram<<<dim3(16, 16), dim3(256), 0, stream>>>(W, Gh);
    k_prep_y<<<dim3(4096), dim3(256), 0, stream>>>(io, c, Y16, z);
    k_tgemm<<<dim3(128, 8), dim3(256), 0, stream>>>(ix, Gh, Th);
    k_ytrans<<<dim3(32, 8, 16), dim3(256), 0, stream>>>(Y16, YT16);
    k_attn<<<dim3(32, 16), dim3(512), 0, stream>>>(Th, Y16, z, P, L);
    k_pv<<<dim3(32, 4, 8), dim3(256), 0, stream>>>(P, YT16, L, out);
}